// Round 3
// baseline (318.497 us; speedup 1.0000x reference)
//
#include <hip/hip_runtime.h>

#define B_DIM 4096
#define H_DIM 1024
#define K_DIM 2048   // IN + H

typedef unsigned short u16;
typedef unsigned int u32;
typedef __attribute__((ext_vector_type(8))) short short8;
typedef __attribute__((ext_vector_type(4))) float f32x4;

typedef const __attribute__((address_space(1))) void* gas_ptr;
typedef __attribute__((address_space(3))) void* las_ptr;

__device__ __forceinline__ void gl_lds16(const u16* g, u16* l) {
    __builtin_amdgcn_global_load_lds((gas_ptr)g, (las_ptr)l, 16, 0, 0);
}
__device__ __forceinline__ float bf2f(u16 v) {
    return __builtin_bit_cast(float, (u32)((u32)v << 16));
}
__device__ __forceinline__ u16 f2bf(float f) {
    u32 u = __builtin_bit_cast(u32, f);
    return (u16)((u + 0x7fffu + ((u >> 16) & 1u)) >> 16);
}
__device__ __forceinline__ float sigm(float x) { return 1.0f / (1.0f + __expf(-x)); }
__device__ __forceinline__ float tanh_f(float x) { return 1.0f - 2.0f / (__expf(2.0f * x) + 1.0f); }

// Dtype probe: Wf entries ~N(0, 1/sqrt(2048)) — as bf16, first 64 u16s are all
// finite with |v| <= 1. If the buffer actually holds f32, every other u16 is
// mantissa junk (uniform): P(all 64 interpret <= 1) ~ 2^-32. Uniform branch.
__device__ __forceinline__ bool probe_is_bf16(const u16* w) {
    bool ok = true;
#pragma unroll
    for (int i = 0; i < 64; ++i) {
        float v = bf2f(w[i]);
        ok = ok && (v == v) && (fabsf(v) <= 1.0f);
    }
    return ok;
}

// ================= bf16-data path (round-2 kernel + probe gate) =================
__global__ __launch_bounds__(256) void lstm_bf16(
    const u16* __restrict__ x, const u16* __restrict__ h_prev, const u16* __restrict__ c_prev,
    const u16* __restrict__ Wf, const u16* __restrict__ Wi, const u16* __restrict__ Wg, const u16* __restrict__ Wo,
    const u16* __restrict__ bf_, const u16* __restrict__ bi_, const u16* __restrict__ bg_, const u16* __restrict__ bo_,
    u16* __restrict__ out) {
    if (!probe_is_bf16(Wf)) return;   // data is f32 -> other kernel handles it

    __shared__ u16 smem[16384];
    u16* sA = smem;
    u16* sB = smem + 4096;

    const int t = threadIdx.x;
    const int w = t >> 6;
    const int l = t & 63;
    const int quad = l >> 4;
    const int l15 = l & 15;
    const int wr = w >> 1;
    const int wc = w & 1;
    const int m0 = blockIdx.x * 128;
    const int j0 = blockIdx.y * 32;

    const int r7 = t & 127;
    const int bk = r7 >> 2;
    const int bn8 = (r7 & 3) * 8;
    const int kswz = ((((bk >> 3) ^ (bn8 >> 3)) << 3) | (bk & 7));
    const u16* WpA = (t < 128) ? Wf : Wi;
    const u16* WpB = (t < 128) ? Wg : Wo;
    const int gA = (t >> 7);
    const int gB = 2 + (t >> 7);

    f32x4 acc[2][4][2];
#pragma unroll
    for (int gi = 0; gi < 2; ++gi)
#pragma unroll
        for (int mi = 0; mi < 4; ++mi)
#pragma unroll
            for (int ni = 0; ni < 2; ++ni)
                acc[gi][mi][ni] = (f32x4){0.f, 0.f, 0.f, 0.f};

    for (int kt = 0; kt < K_DIM / 32; ++kt) {
        const u16* srcA = (kt < 32) ? x : h_prev;
        const int koff = (kt & 31) * 32;
        __syncthreads();
#pragma unroll
        for (int i = 0; i < 2; ++i) {
            int c = i * 256 + t;
            int m = c >> 2, k8 = (c & 3) * 8;
            gl_lds16(srcA + (size_t)(m0 + m) * H_DIM + koff + k8, sA + c * 8);
        }
        short8 bregA = *(const short8*)(WpA + (size_t)(kt * 32 + bk) * H_DIM + j0 + bn8);
        short8 bregB = *(const short8*)(WpB + (size_t)(kt * 32 + bk) * H_DIM + j0 + bn8);
#pragma unroll
        for (int j = 0; j < 8; ++j) sB[gA * 1024 + (bn8 + j) * 32 + kswz] = (u16)bregA[j];
#pragma unroll
        for (int j = 0; j < 8; ++j) sB[gB * 1024 + (bn8 + j) * 32 + kswz] = (u16)bregB[j];
        __syncthreads();

        short8 bfr[2][2];
#pragma unroll
        for (int gi = 0; gi < 2; ++gi) {
            int g = wc * 2 + gi;
#pragma unroll
            for (int ni = 0; ni < 2; ++ni) {
                int n = ni * 16 + l15;
                bfr[gi][ni] = *(const short8*)(sB + g * 1024 + n * 32 + ((quad ^ (n >> 3)) * 8));
            }
        }
#pragma unroll
        for (int mi = 0; mi < 4; ++mi) {
            int m = wr * 64 + mi * 16 + l15;
            short8 afr = *(const short8*)(sA + m * 32 + quad * 8);
#pragma unroll
            for (int gi = 0; gi < 2; ++gi)
#pragma unroll
                for (int ni = 0; ni < 2; ++ni)
                    acc[gi][mi][ni] =
                        __builtin_amdgcn_mfma_f32_16x16x32_bf16(afr, bfr[gi][ni], acc[gi][mi][ni], 0, 0, 0);
        }
    }

    __syncthreads();
#pragma unroll
    for (int gi = 0; gi < 2; ++gi) {
        int g = wc * 2 + gi;
        const u16* bp = (g == 0) ? bf_ : (g == 1) ? bi_ : (g == 2) ? bg_ : bo_;
#pragma unroll
        for (int ni = 0; ni < 2; ++ni) {
            int col = ni * 16 + l15;
            float bias = bf2f(bp[j0 + col]);
#pragma unroll
            for (int mi = 0; mi < 4; ++mi)
#pragma unroll
                for (int rr = 0; rr < 4; ++rr) {
                    int row = wr * 64 + mi * 16 + quad * 4 + rr;
                    float v = acc[gi][mi][ni][rr] + bias;
                    v = (g == 2) ? tanh_f(v) : sigm(v);
                    smem[g * 4096 + row * 32 + col] = f2bf(v);
                }
        }
    }
    __syncthreads();

    const int col = t & 31;
    const int rb = t >> 5;
#pragma unroll
    for (int p = 0; p < 16; ++p) {
        int row = p * 8 + rb;
        float fv = bf2f(smem[0 * 4096 + row * 32 + col]);
        float iv = bf2f(smem[1 * 4096 + row * 32 + col]);
        float gv = bf2f(smem[2 * 4096 + row * 32 + col]);
        float ov = bf2f(smem[3 * 4096 + row * 32 + col]);
        size_t oidx = (size_t)(m0 + row) * H_DIM + j0 + col;
        float cp = bf2f(c_prev[oidx]);
        float cn = fv * cp + iv * gv;
        float hn = ov * tanh_f(cn);
        out[oidx] = f2bf(hn);
        out[(size_t)B_DIM * H_DIM + oidx] = f2bf(cn);
    }
}

// ================= f32-data path: convert to bf16 during LDS staging =================
__global__ __launch_bounds__(256) void lstm_f32(
    const float* __restrict__ x, const float* __restrict__ h_prev, const float* __restrict__ c_prev,
    const float* __restrict__ Wf, const float* __restrict__ Wi, const float* __restrict__ Wg, const float* __restrict__ Wo,
    const float* __restrict__ bf_, const float* __restrict__ bi_, const float* __restrict__ bg_, const float* __restrict__ bo_,
    float* __restrict__ out) {
    if (probe_is_bf16((const u16*)Wf)) return;   // data is bf16 -> other kernel handles it

    __shared__ u16 smem[16384];
    u16* sA = smem;          // [m][k] m<128, k<32
    u16* sB = smem + 4096;   // [g][n][k'] swizzled

    const int t = threadIdx.x;
    const int w = t >> 6;
    const int l = t & 63;
    const int quad = l >> 4;
    const int l15 = l & 15;
    const int wr = w >> 1;
    const int wc = w & 1;
    const int m0 = blockIdx.x * 128;
    const int j0 = blockIdx.y * 32;

    // A staging: thread t -> row t>>1, k-half (t&1)*16 (16 floats -> 16 bf16)
    const int arow = t >> 1;
    const int akh = (t & 1) * 16;
    // B staging: as bf16 path but float4 loads + convert
    const int r7 = t & 127;
    const int bk = r7 >> 2;
    const int bn8 = (r7 & 3) * 8;
    const int kswz = ((((bk >> 3) ^ (bn8 >> 3)) << 3) | (bk & 7));
    const float* WpA = (t < 128) ? Wf : Wi;
    const float* WpB = (t < 128) ? Wg : Wo;
    const int gA = (t >> 7);
    const int gB = 2 + (t >> 7);

    f32x4 acc[2][4][2];
#pragma unroll
    for (int gi = 0; gi < 2; ++gi)
#pragma unroll
        for (int mi = 0; mi < 4; ++mi)
#pragma unroll
            for (int ni = 0; ni < 2; ++ni)
                acc[gi][mi][ni] = (f32x4){0.f, 0.f, 0.f, 0.f};

    for (int kt = 0; kt < K_DIM / 32; ++kt) {
        const float* srcA = (kt < 32) ? x : h_prev;
        const int koff = (kt & 31) * 32;
        __syncthreads();

        // --- A: 4x float4 load, convert, 2x b128 LDS write ---
        const float4* ap = (const float4*)(srcA + (size_t)(m0 + arow) * H_DIM + koff + akh);
        float4 a0 = ap[0], a1 = ap[1], a2 = ap[2], a3 = ap[3];
        short8 p0, p1;
        p0[0] = (short)f2bf(a0.x); p0[1] = (short)f2bf(a0.y); p0[2] = (short)f2bf(a0.z); p0[3] = (short)f2bf(a0.w);
        p0[4] = (short)f2bf(a1.x); p0[5] = (short)f2bf(a1.y); p0[6] = (short)f2bf(a1.z); p0[7] = (short)f2bf(a1.w);
        p1[0] = (short)f2bf(a2.x); p1[1] = (short)f2bf(a2.y); p1[2] = (short)f2bf(a2.z); p1[3] = (short)f2bf(a2.w);
        p1[4] = (short)f2bf(a3.x); p1[5] = (short)f2bf(a3.y); p1[6] = (short)f2bf(a3.z); p1[7] = (short)f2bf(a3.w);
        *(short8*)(sA + arow * 32 + akh) = p0;
        *(short8*)(sA + arow * 32 + akh + 8) = p1;

        // --- B: 2x float4 per gate, convert, transposed swizzled scatter ---
        const float* gpA = WpA + (size_t)(kt * 32 + bk) * H_DIM + j0 + bn8;
        const float* gpB = WpB + (size_t)(kt * 32 + bk) * H_DIM + j0 + bn8;
        float4 c0 = *(const float4*)gpA, c1 = *(const float4*)(gpA + 4);
        float4 d0 = *(const float4*)gpB, d1 = *(const float4*)(gpB + 4);
        sB[gA * 1024 + (bn8 + 0) * 32 + kswz] = f2bf(c0.x);
        sB[gA * 1024 + (bn8 + 1) * 32 + kswz] = f2bf(c0.y);
        sB[gA * 1024 + (bn8 + 2) * 32 + kswz] = f2bf(c0.z);
        sB[gA * 1024 + (bn8 + 3) * 32 + kswz] = f2bf(c0.w);
        sB[gA * 1024 + (bn8 + 4) * 32 + kswz] = f2bf(c1.x);
        sB[gA * 1024 + (bn8 + 5) * 32 + kswz] = f2bf(c1.y);
        sB[gA * 1024 + (bn8 + 6) * 32 + kswz] = f2bf(c1.z);
        sB[gA * 1024 + (bn8 + 7) * 32 + kswz] = f2bf(c1.w);
        sB[gB * 1024 + (bn8 + 0) * 32 + kswz] = f2bf(d0.x);
        sB[gB * 1024 + (bn8 + 1) * 32 + kswz] = f2bf(d0.y);
        sB[gB * 1024 + (bn8 + 2) * 32 + kswz] = f2bf(d0.z);
        sB[gB * 1024 + (bn8 + 3) * 32 + kswz] = f2bf(d0.w);
        sB[gB * 1024 + (bn8 + 4) * 32 + kswz] = f2bf(d1.x);
        sB[gB * 1024 + (bn8 + 5) * 32 + kswz] = f2bf(d1.y);
        sB[gB * 1024 + (bn8 + 6) * 32 + kswz] = f2bf(d1.z);
        sB[gB * 1024 + (bn8 + 7) * 32 + kswz] = f2bf(d1.w);
        __syncthreads();

        short8 bfr[2][2];
#pragma unroll
        for (int gi = 0; gi < 2; ++gi) {
            int g = wc * 2 + gi;
#pragma unroll
            for (int ni = 0; ni < 2; ++ni) {
                int n = ni * 16 + l15;
                bfr[gi][ni] = *(const short8*)(sB + g * 1024 + n * 32 + ((quad ^ (n >> 3)) * 8));
            }
        }
#pragma unroll
        for (int mi = 0; mi < 4; ++mi) {
            int m = wr * 64 + mi * 16 + l15;
            short8 afr = *(const short8*)(sA + m * 32 + quad * 8);
#pragma unroll
            for (int gi = 0; gi < 2; ++gi)
#pragma unroll
                for (int ni = 0; ni < 2; ++ni)
                    acc[gi][mi][ni] =
                        __builtin_amdgcn_mfma_f32_16x16x32_bf16(afr, bfr[gi][ni], acc[gi][mi][ni], 0, 0, 0);
        }
    }

    __syncthreads();
#pragma unroll
    for (int gi = 0; gi < 2; ++gi) {
        int g = wc * 2 + gi;
        const float* bp = (g == 0) ? bf_ : (g == 1) ? bi_ : (g == 2) ? bg_ : bo_;
#pragma unroll
        for (int ni = 0; ni < 2; ++ni) {
            int col = ni * 16 + l15;
            float bias = bp[j0 + col];
#pragma unroll
            for (int mi = 0; mi < 4; ++mi)
#pragma unroll
                for (int rr = 0; rr < 4; ++rr) {
                    int row = wr * 64 + mi * 16 + quad * 4 + rr;
                    float v = acc[gi][mi][ni][rr] + bias;
                    v = (g == 2) ? tanh_f(v) : sigm(v);
                    smem[g * 4096 + row * 32 + col] = f2bf(v);
                }
        }
    }
    __syncthreads();

    const int col = t & 31;
    const int rb = t >> 5;
#pragma unroll
    for (int p = 0; p < 16; ++p) {
        int row = p * 8 + rb;
        float fv = bf2f(smem[0 * 4096 + row * 32 + col]);
        float iv = bf2f(smem[1 * 4096 + row * 32 + col]);
        float gv = bf2f(smem[2 * 4096 + row * 32 + col]);
        float ov = bf2f(smem[3 * 4096 + row * 32 + col]);
        size_t oidx = (size_t)(m0 + row) * H_DIM + j0 + col;
        float cp = c_prev[oidx];
        float cn = fv * cp + iv * gv;
        float hn = ov * tanh_f(cn);
        out[oidx] = hn;
        out[(size_t)B_DIM * H_DIM + oidx] = cn;
    }
}

extern "C" void kernel_launch(void* const* d_in, const int* in_sizes, int n_in,
                              void* d_out, int out_size, void* d_ws, size_t ws_size,
                              hipStream_t stream) {
    dim3 grid(B_DIM / 128, H_DIM / 32);
    lstm_bf16<<<grid, dim3(256), 0, stream>>>(
        (const u16*)d_in[0], (const u16*)d_in[1], (const u16*)d_in[2],
        (const u16*)d_in[3], (const u16*)d_in[5], (const u16*)d_in[7], (const u16*)d_in[9],
        (const u16*)d_in[4], (const u16*)d_in[6], (const u16*)d_in[8], (const u16*)d_in[10],
        (u16*)d_out);
    lstm_f32<<<grid, dim3(256), 0, stream>>>(
        (const float*)d_in[0], (const float*)d_in[1], (const float*)d_in[2],
        (const float*)d_in[3], (const float*)d_in[5], (const float*)d_in[7], (const float*)d_in[9],
        (const float*)d_in[4], (const float*)d_in[6], (const float*)d_in[8], (const float*)d_in[10],
        (float*)d_out);
}

// Round 4
// 243.517 us; speedup vs baseline: 1.3079x; 1.3079x over previous
//
#include <hip/hip_runtime.h>

#define B_DIM 4096
#define H_DIM 1024
#define K_DIM 2048   // IN + H

typedef unsigned short u16;
typedef unsigned int u32;
typedef __attribute__((ext_vector_type(8))) short short8;
typedef __attribute__((ext_vector_type(4))) float f32x4;

typedef const __attribute__((address_space(1))) void* gas_ptr;
typedef __attribute__((address_space(3))) void* las_ptr;

#define WT_ELEMS (4 * H_DIM * K_DIM)       // 8.39M u16
#define AC_ELEMS (B_DIM * K_DIM)           // 8.39M u16
#define WS_NEEDED ((size_t)(WT_ELEMS + AC_ELEMS) * 2)   // 33.55 MB

__device__ __forceinline__ void gl_lds16(const u16* g, u16* l) {
    __builtin_amdgcn_global_load_lds((gas_ptr)g, (las_ptr)l, 16, 0, 0);
}
__device__ __forceinline__ float bf2f(u16 v) {
    return __builtin_bit_cast(float, (u32)((u32)v << 16));
}
__device__ __forceinline__ u16 f2bf(float f) {
    u32 u = __builtin_bit_cast(u32, f);
    return (u16)((u + 0x7fffu + ((u >> 16) & 1u)) >> 16);
}
__device__ __forceinline__ float sigm(float x) { return 1.0f / (1.0f + __expf(-x)); }
__device__ __forceinline__ float tanh_f(float x) { return 1.0f - 2.0f / (__expf(2.0f * x) + 1.0f); }

// ---------- prep_a: x|h f32 -> combined bf16 A[4096][2048] ----------
__global__ __launch_bounds__(256) void prep_a(const float* __restrict__ x, const float* __restrict__ h,
                                              u16* __restrict__ A) {
    int gid = blockIdx.x * 256 + threadIdx.x;
    int e = gid * 8;                    // 8 elements per thread
    int m = e >> 11, c = e & 2047;
    const float* src = (c < 1024) ? (x + (size_t)m * 1024 + c) : (h + (size_t)m * 1024 + (c - 1024));
    float4 v0 = ((const float4*)src)[0], v1 = ((const float4*)src)[1];
    short8 q;
    q[0] = (short)f2bf(v0.x); q[1] = (short)f2bf(v0.y); q[2] = (short)f2bf(v0.z); q[3] = (short)f2bf(v0.w);
    q[4] = (short)f2bf(v1.x); q[5] = (short)f2bf(v1.y); q[6] = (short)f2bf(v1.z); q[7] = (short)f2bf(v1.w);
    *(short8*)(A + e) = q;
}

// ---------- prep_w: W[k][n] f32 -> Wt[g][n][k] bf16, 64x64 LDS transpose tiles ----------
__global__ __launch_bounds__(256) void prep_w(const float* __restrict__ Wf, const float* __restrict__ Wi,
                                              const float* __restrict__ Wg, const float* __restrict__ Wo,
                                              u16* __restrict__ Wt) {
    __shared__ u16 tl[64][72];   // +8 pad keeps short8 alignment, breaks pow-2 stride
    const int t = threadIdx.x;
    const int k0 = blockIdx.x * 64, n0 = blockIdx.y * 64, g = blockIdx.z;
    const float* W = (g == 0) ? Wf : (g == 1) ? Wi : (g == 2) ? Wg : Wo;
    {
        int kl = t >> 2, nc = (t & 3) * 16;
        const float4* src = (const float4*)(W + (size_t)(k0 + kl) * H_DIM + n0 + nc);
        float4 v0 = src[0], v1 = src[1], v2 = src[2], v3 = src[3];
        short8 q0, q1;
        q0[0] = (short)f2bf(v0.x); q0[1] = (short)f2bf(v0.y); q0[2] = (short)f2bf(v0.z); q0[3] = (short)f2bf(v0.w);
        q0[4] = (short)f2bf(v1.x); q0[5] = (short)f2bf(v1.y); q0[6] = (short)f2bf(v1.z); q0[7] = (short)f2bf(v1.w);
        q1[0] = (short)f2bf(v2.x); q1[1] = (short)f2bf(v2.y); q1[2] = (short)f2bf(v2.z); q1[3] = (short)f2bf(v2.w);
        q1[4] = (short)f2bf(v3.x); q1[5] = (short)f2bf(v3.y); q1[6] = (short)f2bf(v3.z); q1[7] = (short)f2bf(v3.w);
        *(short8*)&tl[kl][nc] = q0;
        *(short8*)&tl[kl][nc + 8] = q1;
    }
    __syncthreads();
    {
        int nl = t >> 2, kc = (t & 3) * 16;
        short8 r0, r1;
#pragma unroll
        for (int j = 0; j < 8; ++j) { r0[j] = (short)tl[kc + j][nl]; r1[j] = (short)tl[kc + 8 + j][nl]; }
        u16* dst = Wt + (size_t)g * (H_DIM * K_DIM) + (size_t)(n0 + nl) * K_DIM + k0 + kc;
        *(short8*)dst = r0;
        *(short8*)(dst + 8) = r1;
    }
}

// ---------- main fused GEMM + LSTM (m97 structure, both operands via global_load_lds) ----------
// Block tile: 128 batch-rows x (4 gates x 32 H-cols). 256 threads = 4 waves.
// Wave w: rows [(w>>1)*64, +64), gates {2*(w&1), 2*(w&1)+1}, 32 cols each.
__global__ __launch_bounds__(256) void lstm_gemm(
    const u16* __restrict__ A, const u16* __restrict__ Wt, const float* __restrict__ c_prev,
    const float* __restrict__ bf_, const float* __restrict__ bi_,
    const float* __restrict__ bg_, const float* __restrict__ bo_,
    float* __restrict__ out) {
    // K-loop: sA 128x32 bf16 (8KB) + sB 4x32x32 bf16 (8KB). Epilogue reuses 32KB as gates[4][128][32].
    __shared__ u16 smem[16384];
    u16* sA = smem;
    u16* sB = smem + 4096;

    const int t = threadIdx.x;
    const int w = t >> 6;
    const int l = t & 63;
    const int quad = l >> 4;
    const int l15 = l & 15;
    const int wr = w >> 1;
    const int wc = w & 1;
    const int m0 = blockIdx.x * 128;
    const int j0 = blockIdx.y * 32;

    f32x4 acc[2][4][2];
#pragma unroll
    for (int gi = 0; gi < 2; ++gi)
#pragma unroll
        for (int mi = 0; mi < 4; ++mi)
#pragma unroll
            for (int ni = 0; ni < 2; ++ni)
                acc[gi][mi][ni] = (f32x4){0.f, 0.f, 0.f, 0.f};

    for (int kt = 0; kt < K_DIM / 32; ++kt) {
        __syncthreads();   // prior iteration's frag reads done before LDS overwrite
        // Stage A: 128x32 bf16 = 512 x 16B chunks; dest lane-contiguous per wave call.
#pragma unroll
        for (int i = 0; i < 2; ++i) {
            int c = i * 256 + t;
            int m = c >> 2, k8 = (c & 3) * 8;
            gl_lds16(A + (size_t)(m0 + m) * K_DIM + kt * 32 + k8, sA + c * 8);
        }
        // Stage B: 4 gates x 32 n x 32 k = 512 x 16B chunks from Wt[g][n][k].
#pragma unroll
        for (int i = 0; i < 2; ++i) {
            int c = i * 256 + t;
            int g = c >> 7, c7 = c & 127;
            int n = c7 >> 2, k8 = (c7 & 3) * 8;
            gl_lds16(Wt + (size_t)g * (H_DIM * K_DIM) + (size_t)(j0 + n) * K_DIM + kt * 32 + k8,
                     sB + c * 8);
        }
        __syncthreads();   // drains DMA vmcnt before frag reads

        short8 bfr[2][2];
#pragma unroll
        for (int gi = 0; gi < 2; ++gi) {
            int g = wc * 2 + gi;
#pragma unroll
            for (int ni = 0; ni < 2; ++ni) {
                int n = ni * 16 + l15;
                bfr[gi][ni] = *(const short8*)(sB + g * 1024 + n * 32 + quad * 8);
            }
        }
#pragma unroll
        for (int mi = 0; mi < 4; ++mi) {
            int m = wr * 64 + mi * 16 + l15;
            short8 afr = *(const short8*)(sA + m * 32 + quad * 8);
#pragma unroll
            for (int gi = 0; gi < 2; ++gi)
#pragma unroll
                for (int ni = 0; ni < 2; ++ni)
                    acc[gi][mi][ni] =
                        __builtin_amdgcn_mfma_f32_16x16x32_bf16(afr, bfr[gi][ni], acc[gi][mi][ni], 0, 0, 0);
        }
    }

    __syncthreads();   // done with sA/sB; reuse full 32KB for gate exchange

#pragma unroll
    for (int gi = 0; gi < 2; ++gi) {
        int g = wc * 2 + gi;
        const float* bp = (g == 0) ? bf_ : (g == 1) ? bi_ : (g == 2) ? bg_ : bo_;
#pragma unroll
        for (int ni = 0; ni < 2; ++ni) {
            int col = ni * 16 + l15;
            float bias = bp[j0 + col];
#pragma unroll
            for (int mi = 0; mi < 4; ++mi)
#pragma unroll
                for (int rr = 0; rr < 4; ++rr) {
                    int row = wr * 64 + mi * 16 + quad * 4 + rr;  // verified C/D map (round 3 pass)
                    float v = acc[gi][mi][ni][rr] + bias;
                    v = (g == 2) ? tanh_f(v) : sigm(v);
                    smem[g * 4096 + row * 32 + col] = f2bf(v);
                }
        }
    }
    __syncthreads();

    const int col = t & 31;
    const int rb = t >> 5;
#pragma unroll
    for (int p = 0; p < 16; ++p) {
        int row = p * 8 + rb;
        float fv = bf2f(smem[0 * 4096 + row * 32 + col]);
        float iv = bf2f(smem[1 * 4096 + row * 32 + col]);
        float gv = bf2f(smem[2 * 4096 + row * 32 + col]);
        float ov = bf2f(smem[3 * 4096 + row * 32 + col]);
        size_t oidx = (size_t)(m0 + row) * H_DIM + j0 + col;
        float cp = c_prev[oidx];
        float cn = fv * cp + iv * gv;
        float hn = ov * tanh_f(cn);
        out[oidx] = hn;
        out[(size_t)B_DIM * H_DIM + oidx] = cn;
    }
}

// ---------- fallback (round-3 passing kernel, probe removed): used only if ws too small ----------
__global__ __launch_bounds__(256) void lstm_f32(
    const float* __restrict__ x, const float* __restrict__ h_prev, const float* __restrict__ c_prev,
    const float* __restrict__ Wf, const float* __restrict__ Wi, const float* __restrict__ Wg, const float* __restrict__ Wo,
    const float* __restrict__ bf_, const float* __restrict__ bi_, const float* __restrict__ bg_, const float* __restrict__ bo_,
    float* __restrict__ out) {
    __shared__ u16 smem[16384];
    u16* sA = smem;
    u16* sB = smem + 4096;

    const int t = threadIdx.x;
    const int w = t >> 6;
    const int l = t & 63;
    const int quad = l >> 4;
    const int l15 = l & 15;
    const int wr = w >> 1;
    const int wc = w & 1;
    const int m0 = blockIdx.x * 128;
    const int j0 = blockIdx.y * 32;

    const int arow = t >> 1;
    const int akh = (t & 1) * 16;
    const int r7 = t & 127;
    const int bk = r7 >> 2;
    const int bn8 = (r7 & 3) * 8;
    const int kswz = ((((bk >> 3) ^ (bn8 >> 3)) << 3) | (bk & 7));
    const float* WpA = (t < 128) ? Wf : Wi;
    const float* WpB = (t < 128) ? Wg : Wo;
    const int gA = (t >> 7);
    const int gB = 2 + (t >> 7);

    f32x4 acc[2][4][2];
#pragma unroll
    for (int gi = 0; gi < 2; ++gi)
#pragma unroll
        for (int mi = 0; mi < 4; ++mi)
#pragma unroll
            for (int ni = 0; ni < 2; ++ni)
                acc[gi][mi][ni] = (f32x4){0.f, 0.f, 0.f, 0.f};

    for (int kt = 0; kt < K_DIM / 32; ++kt) {
        const float* srcA = (kt < 32) ? x : h_prev;
        const int koff = (kt & 31) * 32;
        __syncthreads();

        const float4* ap = (const float4*)(srcA + (size_t)(m0 + arow) * H_DIM + koff + akh);
        float4 a0 = ap[0], a1 = ap[1], a2 = ap[2], a3 = ap[3];
        short8 p0, p1;
        p0[0] = (short)f2bf(a0.x); p0[1] = (short)f2bf(a0.y); p0[2] = (short)f2bf(a0.z); p0[3] = (short)f2bf(a0.w);
        p0[4] = (short)f2bf(a1.x); p0[5] = (short)f2bf(a1.y); p0[6] = (short)f2bf(a1.z); p0[7] = (short)f2bf(a1.w);
        p1[0] = (short)f2bf(a2.x); p1[1] = (short)f2bf(a2.y); p1[2] = (short)f2bf(a2.z); p1[3] = (short)f2bf(a2.w);
        p1[4] = (short)f2bf(a3.x); p1[5] = (short)f2bf(a3.y); p1[6] = (short)f2bf(a3.z); p1[7] = (short)f2bf(a3.w);
        *(short8*)(sA + arow * 32 + akh) = p0;
        *(short8*)(sA + arow * 32 + akh + 8) = p1;

        const float* gpA = WpA + (size_t)(kt * 32 + bk) * H_DIM + j0 + bn8;
        const float* gpB = WpB + (size_t)(kt * 32 + bk) * H_DIM + j0 + bn8;
        float4 c0 = *(const float4*)gpA, c1 = *(const float4*)(gpA + 4);
        float4 d0 = *(const float4*)gpB, d1 = *(const float4*)(gpB + 4);
        sB[gA * 1024 + (bn8 + 0) * 32 + kswz] = f2bf(c0.x);
        sB[gA * 1024 + (bn8 + 1) * 32 + kswz] = f2bf(c0.y);
        sB[gA * 1024 + (bn8 + 2) * 32 + kswz] = f2bf(c0.z);
        sB[gA * 1024 + (bn8 + 3) * 32 + kswz] = f2bf(c0.w);
        sB[gA * 1024 + (bn8 + 4) * 32 + kswz] = f2bf(c1.x);
        sB[gA * 1024 + (bn8 + 5) * 32 + kswz] = f2bf(c1.y);
        sB[gA * 1024 + (bn8 + 6) * 32 + kswz] = f2bf(c1.z);
        sB[gA * 1024 + (bn8 + 7) * 32 + kswz] = f2bf(c1.w);
        sB[gB * 1024 + (bn8 + 0) * 32 + kswz] = f2bf(d0.x);
        sB[gB * 1024 + (bn8 + 1) * 32 + kswz] = f2bf(d0.y);
        sB[gB * 1024 + (bn8 + 2) * 32 + kswz] = f2bf(d0.z);
        sB[gB * 1024 + (bn8 + 3) * 32 + kswz] = f2bf(d0.w);
        sB[gB * 1024 + (bn8 + 4) * 32 + kswz] = f2bf(d1.x);
        sB[gB * 1024 + (bn8 + 5) * 32 + kswz] = f2bf(d1.y);
        sB[gB * 1024 + (bn8 + 6) * 32 + kswz] = f2bf(d1.z);
        sB[gB * 1024 + (bn8 + 7) * 32 + kswz] = f2bf(d1.w);
        __syncthreads();

        short8 bfr[2][2];
#pragma unroll
        for (int gi = 0; gi < 2; ++gi) {
            int g = wc * 2 + gi;
#pragma unroll
            for (int ni = 0; ni < 2; ++ni) {
                int n = ni * 16 + l15;
                bfr[gi][ni] = *(const short8*)(sB + g * 1024 + n * 32 + ((quad ^ (n >> 3)) * 8));
            }
        }
#pragma unroll
        for (int mi = 0; mi < 4; ++mi) {
            int m = wr * 64 + mi * 16 + l15;
            short8 afr = *(const short8*)(sA + m * 32 + quad * 8);
#pragma unroll
            for (int gi = 0; gi < 2; ++gi)
#pragma unroll
                for (int ni = 0; ni < 2; ++ni)
                    acc[gi][mi][ni] =
                        __builtin_amdgcn_mfma_f32_16x16x32_bf16(afr, bfr[gi][ni], acc[gi][mi][ni], 0, 0, 0);
        }
    }

    __syncthreads();
#pragma unroll
    for (int gi = 0; gi < 2; ++gi) {
        int g = wc * 2 + gi;
        const float* bp = (g == 0) ? bf_ : (g == 1) ? bi_ : (g == 2) ? bg_ : bo_;
#pragma unroll
        for (int ni = 0; ni < 2; ++ni) {
            int col = ni * 16 + l15;
            float bias = bp[j0 + col];
#pragma unroll
            for (int mi = 0; mi < 4; ++mi)
#pragma unroll
                for (int rr = 0; rr < 4; ++rr) {
                    int row = wr * 64 + mi * 16 + quad * 4 + rr;
                    float v = acc[gi][mi][ni][rr] + bias;
                    v = (g == 2) ? tanh_f(v) : sigm(v);
                    smem[g * 4096 + row * 32 + col] = f2bf(v);
                }
        }
    }
    __syncthreads();

    const int col = t & 31;
    const int rb = t >> 5;
#pragma unroll
    for (int p = 0; p < 16; ++p) {
        int row = p * 8 + rb;
        float fv = bf2f(smem[0 * 4096 + row * 32 + col]);
        float iv = bf2f(smem[1 * 4096 + row * 32 + col]);
        float gv = bf2f(smem[2 * 4096 + row * 32 + col]);
        float ov = bf2f(smem[3 * 4096 + row * 32 + col]);
        size_t oidx = (size_t)(m0 + row) * H_DIM + j0 + col;
        float cp = c_prev[oidx];
        float cn = fv * cp + iv * gv;
        float hn = ov * tanh_f(cn);
        out[oidx] = hn;
        out[(size_t)B_DIM * H_DIM + oidx] = cn;
    }
}

extern "C" void kernel_launch(void* const* d_in, const int* in_sizes, int n_in,
                              void* d_out, int out_size, void* d_ws, size_t ws_size,
                              hipStream_t stream) {
    const float* x   = (const float*)d_in[0];
    const float* hp  = (const float*)d_in[1];
    const float* cp  = (const float*)d_in[2];
    const float* Wf  = (const float*)d_in[3];
    const float* bf_ = (const float*)d_in[4];
    const float* Wi  = (const float*)d_in[5];
    const float* bi_ = (const float*)d_in[6];
    const float* Wg  = (const float*)d_in[7];
    const float* bg_ = (const float*)d_in[8];
    const float* Wo  = (const float*)d_in[9];
    const float* bo_ = (const float*)d_in[10];
    dim3 grid(B_DIM / 128, H_DIM / 32);

    if (ws_size >= WS_NEEDED) {
        u16* Wt = (u16*)d_ws;
        u16* Ac = (u16*)d_ws + WT_ELEMS;
        prep_a<<<dim3(AC_ELEMS / 8 / 256), dim3(256), 0, stream>>>(x, hp, Ac);
        prep_w<<<dim3(K_DIM / 64, H_DIM / 64, 4), dim3(256), 0, stream>>>(Wf, Wi, Wg, Wo, Wt);
        lstm_gemm<<<grid, dim3(256), 0, stream>>>(Ac, Wt, cp, bf_, bi_, bg_, bo_, (float*)d_out);
    } else {
        lstm_f32<<<grid, dim3(256), 0, stream>>>(x, hp, cp, Wf, Wi, Wg, Wo, bf_, bi_, bg_, bo_, (float*)d_out);
    }
}

// Round 5
// 224.368 us; speedup vs baseline: 1.4195x; 1.0853x over previous
//
#include <hip/hip_runtime.h>

#define B_DIM 4096
#define H_DIM 1024
#define K_DIM 2048   // IN + H

typedef unsigned short u16;
typedef unsigned int u32;
typedef __attribute__((ext_vector_type(8))) short short8;
typedef __attribute__((ext_vector_type(4))) float f32x4;

typedef const __attribute__((address_space(1))) void* gas_ptr;
typedef __attribute__((address_space(3))) void* las_ptr;

#define WT_ELEMS (4 * H_DIM * K_DIM)       // 8.39M u16
#define AC_ELEMS (B_DIM * K_DIM)           // 8.39M u16
#define WS_NEEDED ((size_t)(WT_ELEMS + AC_ELEMS) * 2)   // 33.55 MB

__device__ __forceinline__ void gl_lds16(const u16* g, u16* l) {
    __builtin_amdgcn_global_load_lds((gas_ptr)g, (las_ptr)l, 16, 0, 0);
}
__device__ __forceinline__ float bf2f(u16 v) {
    return __builtin_bit_cast(float, (u32)((u32)v << 16));
}
__device__ __forceinline__ u16 f2bf(float f) {
    u32 u = __builtin_bit_cast(u32, f);
    return (u16)((u + 0x7fffu + ((u >> 16) & 1u)) >> 16);
}
__device__ __forceinline__ float sigm(float x) { return 1.0f / (1.0f + __expf(-x)); }
__device__ __forceinline__ float tanh_f(float x) { return 1.0f - 2.0f / (__expf(2.0f * x) + 1.0f); }

// ---------- prep_a: x|h f32 -> combined bf16 A[4096][2048] ----------
__global__ __launch_bounds__(256) void prep_a(const float* __restrict__ x, const float* __restrict__ h,
                                              u16* __restrict__ A) {
    int gid = blockIdx.x * 256 + threadIdx.x;
    int e = gid * 8;
    int m = e >> 11, c = e & 2047;
    const float* src = (c < 1024) ? (x + (size_t)m * 1024 + c) : (h + (size_t)m * 1024 + (c - 1024));
    float4 v0 = ((const float4*)src)[0], v1 = ((const float4*)src)[1];
    short8 q;
    q[0] = (short)f2bf(v0.x); q[1] = (short)f2bf(v0.y); q[2] = (short)f2bf(v0.z); q[3] = (short)f2bf(v0.w);
    q[4] = (short)f2bf(v1.x); q[5] = (short)f2bf(v1.y); q[6] = (short)f2bf(v1.z); q[7] = (short)f2bf(v1.w);
    *(short8*)(A + e) = q;
}

// ---------- prep_w: W[k][n] f32 -> Wt[g][n][k] bf16 ----------
__global__ __launch_bounds__(256) void prep_w(const float* __restrict__ Wf, const float* __restrict__ Wi,
                                              const float* __restrict__ Wg, const float* __restrict__ Wo,
                                              u16* __restrict__ Wt) {
    __shared__ u16 tl[64][72];
    const int t = threadIdx.x;
    const int k0 = blockIdx.x * 64, n0 = blockIdx.y * 64, g = blockIdx.z;
    const float* W = (g == 0) ? Wf : (g == 1) ? Wi : (g == 2) ? Wg : Wo;
    {
        int kl = t >> 2, nc = (t & 3) * 16;
        const float4* src = (const float4*)(W + (size_t)(k0 + kl) * H_DIM + n0 + nc);
        float4 v0 = src[0], v1 = src[1], v2 = src[2], v3 = src[3];
        short8 q0, q1;
        q0[0] = (short)f2bf(v0.x); q0[1] = (short)f2bf(v0.y); q0[2] = (short)f2bf(v0.z); q0[3] = (short)f2bf(v0.w);
        q0[4] = (short)f2bf(v1.x); q0[5] = (short)f2bf(v1.y); q0[6] = (short)f2bf(v1.z); q0[7] = (short)f2bf(v1.w);
        q1[0] = (short)f2bf(v2.x); q1[1] = (short)f2bf(v2.y); q1[2] = (short)f2bf(v2.z); q1[3] = (short)f2bf(v2.w);
        q1[4] = (short)f2bf(v3.x); q1[5] = (short)f2bf(v3.y); q1[6] = (short)f2bf(v3.z); q1[7] = (short)f2bf(v3.w);
        *(short8*)&tl[kl][nc] = q0;
        *(short8*)&tl[kl][nc + 8] = q1;
    }
    __syncthreads();
    {
        int nl = t >> 2, kc = (t & 3) * 16;
        short8 r0, r1;
#pragma unroll
        for (int j = 0; j < 8; ++j) { r0[j] = (short)tl[kc + j][nl]; r1[j] = (short)tl[kc + 8 + j][nl]; }
        u16* dst = Wt + (size_t)g * (H_DIM * K_DIM) + (size_t)(n0 + nl) * K_DIM + k0 + kc;
        *(short8*)dst = r0;
        *(short8*)(dst + 8) = r1;
    }
}

// ---------- main fused GEMM + LSTM ----------
// Block tile: 256 batch-rows x (4 gates x 16 H-cols). 256 threads = 4 waves.
// Wave w: rows [w*64, w*64+64), ALL 4 gates, 16 cols -> all 4 gate values of an
// output element live in the same lane => pure-register epilogue.
// BK=64 (halved barrier count), XOR k-slot swizzle for conflict-free b128 frag reads.
__global__ __launch_bounds__(256) void lstm_gemm(
    const u16* __restrict__ A, const u16* __restrict__ Wt, const float* __restrict__ c_prev,
    const float* __restrict__ bf_, const float* __restrict__ bi_,
    const float* __restrict__ bg_, const float* __restrict__ bo_,
    float* __restrict__ out) {
    __shared__ u16 sA[256 * 64];    // 32 KB  [m][slot] slot = k8 ^ (m&7)
    __shared__ u16 sB[4 * 16 * 64]; //  8 KB  [g][n][slot] slot = k8 ^ (n&7)

    const int t = threadIdx.x;
    const int w = t >> 6;
    const int l = t & 63;
    const int quad = l >> 4;
    const int l15 = l & 15;
    const int m0 = blockIdx.x * 256;
    const int j0 = blockIdx.y * 16;

    f32x4 acc[4][4];   // [gate][mi]
#pragma unroll
    for (int g = 0; g < 4; ++g)
#pragma unroll
        for (int mi = 0; mi < 4; ++mi)
            acc[g][mi] = (f32x4){0.f, 0.f, 0.f, 0.f};

    // loop-invariant staging geometry
    const int v7 = l15 & 7;   // row/col low bits for read-side swizzle

    for (int kt = 0; kt < K_DIM / 64; ++kt) {
        __syncthreads();   // prior iteration's frag reads done
        // Stage A: 256x64 bf16 = 2048 x 16B chunks, 8 per thread; dest lane-contiguous.
#pragma unroll
        for (int i = 0; i < 8; ++i) {
            int c = i * 256 + t;
            int m = c >> 3, slot = c & 7;
            int k8 = (slot ^ (m & 7)) * 8;
            gl_lds16(A + (size_t)(m0 + m) * K_DIM + kt * 64 + k8, sA + c * 8);
        }
        // Stage B: 4x16x64 bf16 = 512 x 16B chunks, 2 per thread.
#pragma unroll
        for (int i = 0; i < 2; ++i) {
            int c = i * 256 + t;
            int g = c >> 7, r = c & 127;
            int n = r >> 3, slot = r & 7;
            int k8 = (slot ^ (n & 7)) * 8;
            gl_lds16(Wt + (size_t)g * (H_DIM * K_DIM) + (size_t)(j0 + n) * K_DIM + kt * 64 + k8,
                     sB + c * 8);
        }
        __syncthreads();   // drain DMA before frag reads

#pragma unroll
        for (int s = 0; s < 2; ++s) {
            const int sl = ((s * 4 + quad) ^ v7) * 8;   // swizzled k-slot offset (u16)
            short8 bfr[4];
#pragma unroll
            for (int g = 0; g < 4; ++g)
                bfr[g] = *(const short8*)(sB + g * 1024 + l15 * 64 + sl);
            short8 afr[4];
#pragma unroll
            for (int mi = 0; mi < 4; ++mi)
                afr[mi] = *(const short8*)(sA + (w * 64 + mi * 16 + l15) * 64 + sl);
#pragma unroll
            for (int g = 0; g < 4; ++g)
#pragma unroll
                for (int mi = 0; mi < 4; ++mi)
                    acc[g][mi] = __builtin_amdgcn_mfma_f32_16x16x32_bf16(afr[mi], bfr[g], acc[g][mi], 0, 0, 0);
        }
    }

    // -------- register epilogue: no LDS, no barriers --------
    const int col = j0 + l15;
    const float bF = bf_[col], bI = bi_[col], bG = bg_[col], bO = bo_[col];
#pragma unroll
    for (int mi = 0; mi < 4; ++mi) {
        const int rowbase = m0 + w * 64 + mi * 16 + quad * 4;  // C/D map: col=lane&15, row=quad*4+reg
        // issue the 4 c_prev loads early
        float cp[4];
#pragma unroll
        for (int rr = 0; rr < 4; ++rr)
            cp[rr] = c_prev[(size_t)(rowbase + rr) * H_DIM + col];
#pragma unroll
        for (int rr = 0; rr < 4; ++rr) {
            float fv = sigm(acc[0][mi][rr] + bF);
            float iv = sigm(acc[1][mi][rr] + bI);
            float gv = tanh_f(acc[2][mi][rr] + bG);
            float ov = sigm(acc[3][mi][rr] + bO);
            float cn = fv * cp[rr] + iv * gv;
            float hn = ov * tanh_f(cn);
            size_t idx = (size_t)(rowbase + rr) * H_DIM + col;
            out[idx] = hn;
            out[(size_t)B_DIM * H_DIM + idx] = cn;
        }
    }
}

// ---------- fallback (round-3 passing kernel): used only if ws too small ----------
__global__ __launch_bounds__(256) void lstm_f32(
    const float* __restrict__ x, const float* __restrict__ h_prev, const float* __restrict__ c_prev,
    const float* __restrict__ Wf, const float* __restrict__ Wi, const float* __restrict__ Wg, const float* __restrict__ Wo,
    const float* __restrict__ bf_, const float* __restrict__ bi_, const float* __restrict__ bg_, const float* __restrict__ bo_,
    float* __restrict__ out) {
    __shared__ u16 smem[16384];
    u16* sA = smem;
    u16* sB = smem + 4096;

    const int t = threadIdx.x;
    const int w = t >> 6;
    const int l = t & 63;
    const int quad = l >> 4;
    const int l15 = l & 15;
    const int wr = w >> 1;
    const int wc = w & 1;
    const int m0 = blockIdx.x * 128;
    const int j0 = blockIdx.y * 32;

    const int arow = t >> 1;
    const int akh = (t & 1) * 16;
    const int r7 = t & 127;
    const int bk = r7 >> 2;
    const int bn8 = (r7 & 3) * 8;
    const int kswz = ((((bk >> 3) ^ (bn8 >> 3)) << 3) | (bk & 7));
    const float* WpA = (t < 128) ? Wf : Wi;
    const float* WpB = (t < 128) ? Wg : Wo;
    const int gA = (t >> 7);
    const int gB = 2 + (t >> 7);

    f32x4 acc[2][4][2];
#pragma unroll
    for (int gi = 0; gi < 2; ++gi)
#pragma unroll
        for (int mi = 0; mi < 4; ++mi)
#pragma unroll
            for (int ni = 0; ni < 2; ++ni)
                acc[gi][mi][ni] = (f32x4){0.f, 0.f, 0.f, 0.f};

    for (int kt = 0; kt < K_DIM / 32; ++kt) {
        const float* srcA = (kt < 32) ? x : h_prev;
        const int koff = (kt & 31) * 32;
        __syncthreads();

        const float4* ap = (const float4*)(srcA + (size_t)(m0 + arow) * H_DIM + koff + akh);
        float4 a0 = ap[0], a1 = ap[1], a2 = ap[2], a3 = ap[3];
        short8 p0, p1;
        p0[0] = (short)f2bf(a0.x); p0[1] = (short)f2bf(a0.y); p0[2] = (short)f2bf(a0.z); p0[3] = (short)f2bf(a0.w);
        p0[4] = (short)f2bf(a1.x); p0[5] = (short)f2bf(a1.y); p0[6] = (short)f2bf(a1.z); p0[7] = (short)f2bf(a1.w);
        p1[0] = (short)f2bf(a2.x); p1[1] = (short)f2bf(a2.y); p1[2] = (short)f2bf(a2.z); p1[3] = (short)f2bf(a2.w);
        p1[4] = (short)f2bf(a3.x); p1[5] = (short)f2bf(a3.y); p1[6] = (short)f2bf(a3.z); p1[7] = (short)f2bf(a3.w);
        *(short8*)(sA + arow * 32 + akh) = p0;
        *(short8*)(sA + arow * 32 + akh + 8) = p1;

        const float* gpA = WpA + (size_t)(kt * 32 + bk) * H_DIM + j0 + bn8;
        const float* gpB = WpB + (size_t)(kt * 32 + bk) * H_DIM + j0 + bn8;
        float4 c0 = *(const float4*)gpA, c1 = *(const float4*)(gpA + 4);
        float4 d0 = *(const float4*)gpB, d1 = *(const float4*)(gpB + 4);
        sB[gA * 1024 + (bn8 + 0) * 32 + kswz] = f2bf(c0.x);
        sB[gA * 1024 + (bn8 + 1) * 32 + kswz] = f2bf(c0.y);
        sB[gA * 1024 + (bn8 + 2) * 32 + kswz] = f2bf(c0.z);
        sB[gA * 1024 + (bn8 + 3) * 32 + kswz] = f2bf(c0.w);
        sB[gA * 1024 + (bn8 + 4) * 32 + kswz] = f2bf(c1.x);
        sB[gA * 1024 + (bn8 + 5) * 32 + kswz] = f2bf(c1.y);
        sB[gA * 1024 + (bn8 + 6) * 32 + kswz] = f2bf(c1.z);
        sB[gA * 1024 + (bn8 + 7) * 32 + kswz] = f2bf(c1.w);
        sB[gB * 1024 + (bn8 + 0) * 32 + kswz] = f2bf(d0.x);
        sB[gB * 1024 + (bn8 + 1) * 32 + kswz] = f2bf(d0.y);
        sB[gB * 1024 + (bn8 + 2) * 32 + kswz] = f2bf(d0.z);
        sB[gB * 1024 + (bn8 + 3) * 32 + kswz] = f2bf(d0.w);
        sB[gB * 1024 + (bn8 + 4) * 32 + kswz] = f2bf(d1.x);
        sB[gB * 1024 + (bn8 + 5) * 32 + kswz] = f2bf(d1.y);
        sB[gB * 1024 + (bn8 + 6) * 32 + kswz] = f2bf(d1.z);
        sB[gB * 1024 + (bn8 + 7) * 32 + kswz] = f2bf(d1.w);
        __syncthreads();

        short8 bfr[2][2];
#pragma unroll
        for (int gi = 0; gi < 2; ++gi) {
            int g = wc * 2 + gi;
#pragma unroll
            for (int ni = 0; ni < 2; ++ni) {
                int n = ni * 16 + l15;
                bfr[gi][ni] = *(const short8*)(sB + g * 1024 + n * 32 + ((quad ^ (n >> 3)) * 8));
            }
        }
#pragma unroll
        for (int mi = 0; mi < 4; ++mi) {
            int m = wr * 64 + mi * 16 + l15;
            short8 afr = *(const short8*)(sA + m * 32 + quad * 8);
#pragma unroll
            for (int gi = 0; gi < 2; ++gi)
#pragma unroll
                for (int ni = 0; ni < 2; ++ni)
                    acc[gi][mi][ni] =
                        __builtin_amdgcn_mfma_f32_16x16x32_bf16(afr, bfr[gi][ni], acc[gi][mi][ni], 0, 0, 0);
        }
    }

    __syncthreads();
#pragma unroll
    for (int gi = 0; gi < 2; ++gi) {
        int g = wc * 2 + gi;
        const float* bp = (g == 0) ? bf_ : (g == 1) ? bi_ : (g == 2) ? bg_ : bo_;
#pragma unroll
        for (int ni = 0; ni < 2; ++ni) {
            int col = ni * 16 + l15;
            float bias = bp[j0 + col];
#pragma unroll
            for (int mi = 0; mi < 4; ++mi)
#pragma unroll
                for (int rr = 0; rr < 4; ++rr) {
                    int row = wr * 64 + mi * 16 + quad * 4 + rr;
                    float v = acc[gi][mi][ni][rr] + bias;
                    v = (g == 2) ? tanh_f(v) : sigm(v);
                    smem[g * 4096 + row * 32 + col] = f2bf(v);
                }
        }
    }
    __syncthreads();

    const int col = t & 31;
    const int rb = t >> 5;
#pragma unroll
    for (int p = 0; p < 16; ++p) {
        int row = p * 8 + rb;
        float fv = bf2f(smem[0 * 4096 + row * 32 + col]);
        float iv = bf2f(smem[1 * 4096 + row * 32 + col]);
        float gv = bf2f(smem[2 * 4096 + row * 32 + col]);
        float ov = bf2f(smem[3 * 4096 + row * 32 + col]);
        size_t oidx = (size_t)(m0 + row) * H_DIM + j0 + col;
        float cp = c_prev[oidx];
        float cn = fv * cp + iv * gv;
        float hn = ov * tanh_f(cn);
        out[oidx] = hn;
        out[(size_t)B_DIM * H_DIM + oidx] = cn;
    }
}

extern "C" void kernel_launch(void* const* d_in, const int* in_sizes, int n_in,
                              void* d_out, int out_size, void* d_ws, size_t ws_size,
                              hipStream_t stream) {
    const float* x   = (const float*)d_in[0];
    const float* hp  = (const float*)d_in[1];
    const float* cp  = (const float*)d_in[2];
    const float* Wf  = (const float*)d_in[3];
    const float* bf_ = (const float*)d_in[4];
    const float* Wi  = (const float*)d_in[5];
    const float* bi_ = (const float*)d_in[6];
    const float* Wg  = (const float*)d_in[7];
    const float* bg_ = (const float*)d_in[8];
    const float* Wo  = (const float*)d_in[9];
    const float* bo_ = (const float*)d_in[10];

    if (ws_size >= WS_NEEDED) {
        u16* Wt = (u16*)d_ws;
        u16* Ac = (u16*)d_ws + WT_ELEMS;
        prep_a<<<dim3(AC_ELEMS / 8 / 256), dim3(256), 0, stream>>>(x, hp, Ac);
        prep_w<<<dim3(K_DIM / 64, H_DIM / 64, 4), dim3(256), 0, stream>>>(Wf, Wi, Wg, Wo, Wt);
        lstm_gemm<<<dim3(B_DIM / 256, H_DIM / 16), dim3(256), 0, stream>>>(
            Ac, Wt, cp, bf_, bi_, bg_, bo_, (float*)d_out);
    } else {
        lstm_f32<<<dim3(B_DIM / 128, H_DIM / 32), dim3(256), 0, stream>>>(
            x, hp, cp, Wf, Wi, Wg, Wo, bf_, bi_, bg_, bo_, (float*)d_out);
    }
}

// Round 6
// 211.897 us; speedup vs baseline: 1.5031x; 1.0589x over previous
//
#include <hip/hip_runtime.h>

#define B_DIM 4096
#define H_DIM 1024
#define K_DIM 2048   // IN + H

typedef unsigned short u16;
typedef unsigned int u32;
typedef __attribute__((ext_vector_type(8))) short short8;
typedef __attribute__((ext_vector_type(4))) float f32x4;

typedef const __attribute__((address_space(1))) void* gas_ptr;
typedef __attribute__((address_space(3))) void* las_ptr;

#define WT_ELEMS (4 * H_DIM * K_DIM)       // 8.39M u16
#define AC_ELEMS (B_DIM * K_DIM)           // 8.39M u16
#define WS_NEEDED ((size_t)(WT_ELEMS + AC_ELEMS) * 2)   // 33.55 MB

__device__ __forceinline__ void gl_lds16(const u16* g, u16* l) {
    __builtin_amdgcn_global_load_lds((gas_ptr)g, (las_ptr)l, 16, 0, 0);
}
__device__ __forceinline__ float bf2f(u16 v) {
    return __builtin_bit_cast(float, (u32)((u32)v << 16));
}
__device__ __forceinline__ u16 f2bf(float f) {
    u32 u = __builtin_bit_cast(u32, f);
    return (u16)((u + 0x7fffu + ((u >> 16) & 1u)) >> 16);
}
__device__ __forceinline__ float sigm(float x) { return 1.0f / (1.0f + __expf(-x)); }
__device__ __forceinline__ float tanh_f(float x) { return 1.0f - 2.0f / (__expf(2.0f * x) + 1.0f); }

// ---------- merged prep: blocks [0,4096) convert A; blocks [4096,6144) transpose W ----------
// Running both halves in ONE launch lets them overlap across CUs (serial launches
// in the captured graph would add ~10 us of wall time).
__global__ __launch_bounds__(256) void prep_all(const float* __restrict__ x, const float* __restrict__ h,
                                                const float* __restrict__ Wf, const float* __restrict__ Wi,
                                                const float* __restrict__ Wg, const float* __restrict__ Wo,
                                                u16* __restrict__ A, u16* __restrict__ Wt) {
    __shared__ u16 tl[64][72];
    const int t = threadIdx.x;
    if (blockIdx.x < 4096) {
        // ---- prep_a: x|h f32 -> combined bf16 A[4096][2048] ----
        int e = (blockIdx.x * 256 + t) * 8;
        int m = e >> 11, c = e & 2047;
        const float* src = (c < 1024) ? (x + (size_t)m * 1024 + c) : (h + (size_t)m * 1024 + (c - 1024));
        float4 v0 = ((const float4*)src)[0], v1 = ((const float4*)src)[1];
        short8 q;
        q[0] = (short)f2bf(v0.x); q[1] = (short)f2bf(v0.y); q[2] = (short)f2bf(v0.z); q[3] = (short)f2bf(v0.w);
        q[4] = (short)f2bf(v1.x); q[5] = (short)f2bf(v1.y); q[6] = (short)f2bf(v1.z); q[7] = (short)f2bf(v1.w);
        *(short8*)(A + e) = q;
    } else {
        // ---- prep_w: W[k][n] f32 -> Wt[g][n][k] bf16, 64x64 LDS transpose tile ----
        int bid = blockIdx.x - 4096;                  // 2048 = 32 k-tiles x 16 n-tiles x 4 gates
        const int k0 = (bid & 31) * 64, n0 = ((bid >> 5) & 15) * 64, g = bid >> 9;
        const float* W = (g == 0) ? Wf : (g == 1) ? Wi : (g == 2) ? Wg : Wo;
        {
            int kl = t >> 2, nc = (t & 3) * 16;
            const float4* src = (const float4*)(W + (size_t)(k0 + kl) * H_DIM + n0 + nc);
            float4 v0 = src[0], v1 = src[1], v2 = src[2], v3 = src[3];
            short8 q0, q1;
            q0[0] = (short)f2bf(v0.x); q0[1] = (short)f2bf(v0.y); q0[2] = (short)f2bf(v0.z); q0[3] = (short)f2bf(v0.w);
            q0[4] = (short)f2bf(v1.x); q0[5] = (short)f2bf(v1.y); q0[6] = (short)f2bf(v1.z); q0[7] = (short)f2bf(v1.w);
            q1[0] = (short)f2bf(v2.x); q1[1] = (short)f2bf(v2.y); q1[2] = (short)f2bf(v2.z); q1[3] = (short)f2bf(v2.w);
            q1[4] = (short)f2bf(v3.x); q1[5] = (short)f2bf(v3.y); q1[6] = (short)f2bf(v3.z); q1[7] = (short)f2bf(v3.w);
            *(short8*)&tl[kl][nc] = q0;
            *(short8*)&tl[kl][nc + 8] = q1;
        }
        __syncthreads();
        {
            int nl = t >> 2, kc = (t & 3) * 16;
            short8 r0, r1;
#pragma unroll
            for (int j = 0; j < 8; ++j) { r0[j] = (short)tl[kc + j][nl]; r1[j] = (short)tl[kc + 8 + j][nl]; }
            u16* dst = Wt + (size_t)g * (H_DIM * K_DIM) + (size_t)(n0 + nl) * K_DIM + k0 + kc;
            *(short8*)dst = r0;
            *(short8*)(dst + 8) = r1;
        }
    }
}

// ---------- main fused GEMM + LSTM ----------
// Block tile: 128 batch-rows x (4 gates x 32 H-cols) = m97 proportions. 256 threads = 4 waves (2x2).
// Wave (wr,wc): rows wr*64..+64, ALL 4 gates, cols wc*16..+16 -> all 4 gate values of an
// output element stay in one lane => pure-register epilogue.
// BK=64; XOR k-slot swizzle keeps b128 frag reads conflict-free (verified round 5: 0 conflicts).
__global__ __launch_bounds__(256) void lstm_gemm(
    const u16* __restrict__ A, const u16* __restrict__ Wt, const float* __restrict__ c_prev,
    const float* __restrict__ bf_, const float* __restrict__ bi_,
    const float* __restrict__ bg_, const float* __restrict__ bo_,
    float* __restrict__ out) {
    __shared__ u16 sA[128 * 64];    // 16 KB  [m][slot]   slot = k8 ^ (m&7)
    __shared__ u16 sB[4 * 32 * 64]; // 16 KB  [g][n][slot] slot = k8 ^ (n&7)

    const int t = threadIdx.x;
    const int w = t >> 6;
    const int l = t & 63;
    const int quad = l >> 4;
    const int l15 = l & 15;
    const int wr = w >> 1;
    const int wc = w & 1;
    const int m0 = blockIdx.x * 128;
    const int j0 = blockIdx.y * 32;

    f32x4 acc[4][4];   // [gate][mi]
#pragma unroll
    for (int g = 0; g < 4; ++g)
#pragma unroll
        for (int mi = 0; mi < 4; ++mi)
            acc[g][mi] = (f32x4){0.f, 0.f, 0.f, 0.f};

    // Hoisted DMA source pointers (advance by 64 u16 per K-iter).
    const u16* pA[4];
    const u16* pB[4];
#pragma unroll
    for (int i = 0; i < 4; ++i) {
        int c = i * 256 + t;
        int m = c >> 3, slot = c & 7;
        pA[i] = A + (size_t)(m0 + m) * K_DIM + (slot ^ (m & 7)) * 8;
    }
#pragma unroll
    for (int i = 0; i < 4; ++i) {
        int c = i * 256 + t;
        int g = c >> 8, r = c & 255;
        int n = r >> 3, slot = r & 7;
        pB[i] = Wt + (size_t)g * (H_DIM * K_DIM) + (size_t)(j0 + n) * K_DIM + (slot ^ (n & 7)) * 8;
    }
    const int v7 = l15 & 7;

    for (int kt = 0; kt < K_DIM / 64; ++kt) {
        __syncthreads();   // prior iteration's frag reads done
#pragma unroll
        for (int i = 0; i < 4; ++i) {
            gl_lds16(pA[i], sA + (i * 256 + t) * 8);
            pA[i] += 64;
        }
#pragma unroll
        for (int i = 0; i < 4; ++i) {
            gl_lds16(pB[i], sB + (i * 256 + t) * 8);
            pB[i] += 64;
        }
        __syncthreads();   // drain DMA before frag reads

#pragma unroll
        for (int s = 0; s < 2; ++s) {
            const int sl = ((s * 4 + quad) ^ v7) * 8;
            short8 bfr[4];
#pragma unroll
            for (int g = 0; g < 4; ++g)
                bfr[g] = *(const short8*)(sB + g * 2048 + (wc * 16 + l15) * 64 + sl);
            short8 afr[4];
#pragma unroll
            for (int mi = 0; mi < 4; ++mi)
                afr[mi] = *(const short8*)(sA + (wr * 64 + mi * 16 + l15) * 64 + sl);
#pragma unroll
            for (int g = 0; g < 4; ++g)
#pragma unroll
                for (int mi = 0; mi < 4; ++mi)
                    acc[g][mi] = __builtin_amdgcn_mfma_f32_16x16x32_bf16(afr[mi], bfr[g], acc[g][mi], 0, 0, 0);
        }
    }

    // -------- register epilogue: no LDS, no barriers --------
    const int col = j0 + wc * 16 + l15;
    const float bF = bf_[col], bI = bi_[col], bG = bg_[col], bO = bo_[col];
#pragma unroll
    for (int mi = 0; mi < 4; ++mi) {
        const int rowbase = m0 + wr * 64 + mi * 16 + quad * 4;  // C/D map: col=lane&15, row=quad*4+reg
        float cp[4];
#pragma unroll
        for (int rr = 0; rr < 4; ++rr)
            cp[rr] = c_prev[(size_t)(rowbase + rr) * H_DIM + col];
#pragma unroll
        for (int rr = 0; rr < 4; ++rr) {
            float fv = sigm(acc[0][mi][rr] + bF);
            float iv = sigm(acc[1][mi][rr] + bI);
            float gv = tanh_f(acc[2][mi][rr] + bG);
            float ov = sigm(acc[3][mi][rr] + bO);
            float cn = fv * cp[rr] + iv * gv;
            float hn = ov * tanh_f(cn);
            size_t idx = (size_t)(rowbase + rr) * H_DIM + col;
            out[idx] = hn;
            out[(size_t)B_DIM * H_DIM + idx] = cn;
        }
    }
}

// ---------- fallback (round-3 passing kernel): used only if ws too small ----------
__global__ __launch_bounds__(256) void lstm_f32(
    const float* __restrict__ x, const float* __restrict__ h_prev, const float* __restrict__ c_prev,
    const float* __restrict__ Wf, const float* __restrict__ Wi, const float* __restrict__ Wg, const float* __restrict__ Wo,
    const float* __restrict__ bf_, const float* __restrict__ bi_, const float* __restrict__ bg_, const float* __restrict__ bo_,
    float* __restrict__ out) {
    __shared__ u16 smem[16384];
    u16* sA = smem;
    u16* sB = smem + 4096;

    const int t = threadIdx.x;
    const int w = t >> 6;
    const int l = t & 63;
    const int quad = l >> 4;
    const int l15 = l & 15;
    const int wr = w >> 1;
    const int wc = w & 1;
    const int m0 = blockIdx.x * 128;
    const int j0 = blockIdx.y * 32;

    const int arow = t >> 1;
    const int akh = (t & 1) * 16;
    const int r7 = t & 127;
    const int bk = r7 >> 2;
    const int bn8 = (r7 & 3) * 8;
    const int kswz = ((((bk >> 3) ^ (bn8 >> 3)) << 3) | (bk & 7));
    const float* WpA = (t < 128) ? Wf : Wi;
    const float* WpB = (t < 128) ? Wg : Wo;
    const int gA = (t >> 7);
    const int gB = 2 + (t >> 7);

    f32x4 acc[2][4][2];
#pragma unroll
    for (int gi = 0; gi < 2; ++gi)
#pragma unroll
        for (int mi = 0; mi < 4; ++mi)
#pragma unroll
            for (int ni = 0; ni < 2; ++ni)
                acc[gi][mi][ni] = (f32x4){0.f, 0.f, 0.f, 0.f};

    for (int kt = 0; kt < K_DIM / 32; ++kt) {
        const float* srcA = (kt < 32) ? x : h_prev;
        const int koff = (kt & 31) * 32;
        __syncthreads();

        const float4* ap = (const float4*)(srcA + (size_t)(m0 + arow) * H_DIM + koff + akh);
        float4 a0 = ap[0], a1 = ap[1], a2 = ap[2], a3 = ap[3];
        short8 p0, p1;
        p0[0] = (short)f2bf(a0.x); p0[1] = (short)f2bf(a0.y); p0[2] = (short)f2bf(a0.z); p0[3] = (short)f2bf(a0.w);
        p0[4] = (short)f2bf(a1.x); p0[5] = (short)f2bf(a1.y); p0[6] = (short)f2bf(a1.z); p0[7] = (short)f2bf(a1.w);
        p1[0] = (short)f2bf(a2.x); p1[1] = (short)f2bf(a2.y); p1[2] = (short)f2bf(a2.z); p1[3] = (short)f2bf(a2.w);
        p1[4] = (short)f2bf(a3.x); p1[5] = (short)f2bf(a3.y); p1[6] = (short)f2bf(a3.z); p1[7] = (short)f2bf(a3.w);
        *(short8*)(sA + arow * 32 + akh) = p0;
        *(short8*)(sA + arow * 32 + akh + 8) = p1;

        const float* gpA = WpA + (size_t)(kt * 32 + bk) * H_DIM + j0 + bn8;
        const float* gpB = WpB + (size_t)(kt * 32 + bk) * H_DIM + j0 + bn8;
        float4 c0 = *(const float4*)gpA, c1 = *(const float4*)(gpA + 4);
        float4 d0 = *(const float4*)gpB, d1 = *(const float4*)(gpB + 4);
        sB[gA * 1024 + (bn8 + 0) * 32 + kswz] = f2bf(c0.x);
        sB[gA * 1024 + (bn8 + 1) * 32 + kswz] = f2bf(c0.y);
        sB[gA * 1024 + (bn8 + 2) * 32 + kswz] = f2bf(c0.z);
        sB[gA * 1024 + (bn8 + 3) * 32 + kswz] = f2bf(c0.w);
        sB[gA * 1024 + (bn8 + 4) * 32 + kswz] = f2bf(c1.x);
        sB[gA * 1024 + (bn8 + 5) * 32 + kswz] = f2bf(c1.y);
        sB[gA * 1024 + (bn8 + 6) * 32 + kswz] = f2bf(c1.z);
        sB[gA * 1024 + (bn8 + 7) * 32 + kswz] = f2bf(c1.w);
        sB[gB * 1024 + (bn8 + 0) * 32 + kswz] = f2bf(d0.x);
        sB[gB * 1024 + (bn8 + 1) * 32 + kswz] = f2bf(d0.y);
        sB[gB * 1024 + (bn8 + 2) * 32 + kswz] = f2bf(d0.z);
        sB[gB * 1024 + (bn8 + 3) * 32 + kswz] = f2bf(d0.w);
        sB[gB * 1024 + (bn8 + 4) * 32 + kswz] = f2bf(d1.x);
        sB[gB * 1024 + (bn8 + 5) * 32 + kswz] = f2bf(d1.y);
        sB[gB * 1024 + (bn8 + 6) * 32 + kswz] = f2bf(d1.z);
        sB[gB * 1024 + (bn8 + 7) * 32 + kswz] = f2bf(d1.w);
        __syncthreads();

        short8 bfr[2][2];
#pragma unroll
        for (int gi = 0; gi < 2; ++gi) {
            int g = wc * 2 + gi;
#pragma unroll
            for (int ni = 0; ni < 2; ++ni) {
                int n = ni * 16 + l15;
                bfr[gi][ni] = *(const short8*)(sB + g * 1024 + n * 32 + ((quad ^ (n >> 3)) * 8));
            }
        }
#pragma unroll
        for (int mi = 0; mi < 4; ++mi) {
            int m = wr * 64 + mi * 16 + l15;
            short8 afr = *(const short8*)(sA + m * 32 + quad * 8);
#pragma unroll
            for (int gi = 0; gi < 2; ++gi)
#pragma unroll
                for (int ni = 0; ni < 2; ++ni)
                    acc[gi][mi][ni] =
                        __builtin_amdgcn_mfma_f32_16x16x32_bf16(afr, bfr[gi][ni], acc[gi][mi][ni], 0, 0, 0);
        }
    }

    __syncthreads();
#pragma unroll
    for (int gi = 0; gi < 2; ++gi) {
        int g = wc * 2 + gi;
        const float* bp = (g == 0) ? bf_ : (g == 1) ? bi_ : (g == 2) ? bg_ : bo_;
#pragma unroll
        for (int ni = 0; ni < 2; ++ni) {
            int col = ni * 16 + l15;
            float bias = bp[j0 + col];
#pragma unroll
            for (int mi = 0; mi < 4; ++mi)
#pragma unroll
                for (int rr = 0; rr < 4; ++rr) {
                    int row = wr * 64 + mi * 16 + quad * 4 + rr;
                    float v = acc[gi][mi][ni][rr] + bias;
                    v = (g == 2) ? tanh_f(v) : sigm(v);
                    smem[g * 4096 + row * 32 + col] = f2bf(v);
                }
        }
    }
    __syncthreads();

    const int col = t & 31;
    const int rb = t >> 5;
#pragma unroll
    for (int p = 0; p < 16; ++p) {
        int row = p * 8 + rb;
        float fv = bf2f(smem[0 * 4096 + row * 32 + col]);
        float iv = bf2f(smem[1 * 4096 + row * 32 + col]);
        float gv = bf2f(smem[2 * 4096 + row * 32 + col]);
        float ov = bf2f(smem[3 * 4096 + row * 32 + col]);
        size_t oidx = (size_t)(m0 + row) * H_DIM + j0 + col;
        float cp = c_prev[oidx];
        float cn = fv * cp + iv * gv;
        float hn = ov * tanh_f(cn);
        out[oidx] = hn;
        out[(size_t)B_DIM * H_DIM + oidx] = cn;
    }
}

extern "C" void kernel_launch(void* const* d_in, const int* in_sizes, int n_in,
                              void* d_out, int out_size, void* d_ws, size_t ws_size,
                              hipStream_t stream) {
    const float* x   = (const float*)d_in[0];
    const float* hp  = (const float*)d_in[1];
    const float* cp  = (const float*)d_in[2];
    const float* Wf  = (const float*)d_in[3];
    const float* bf_ = (const float*)d_in[4];
    const float* Wi  = (const float*)d_in[5];
    const float* bi_ = (const float*)d_in[6];
    const float* Wg  = (const float*)d_in[7];
    const float* bg_ = (const float*)d_in[8];
    const float* Wo  = (const float*)d_in[9];
    const float* bo_ = (const float*)d_in[10];

    if (ws_size >= WS_NEEDED) {
        u16* Wt = (u16*)d_ws;
        u16* Ac = (u16*)d_ws + WT_ELEMS;
        prep_all<<<dim3(4096 + 2048), dim3(256), 0, stream>>>(x, hp, Wf, Wi, Wg, Wo, Ac, Wt);
        lstm_gemm<<<dim3(B_DIM / 128, H_DIM / 32), dim3(256), 0, stream>>>(
            Ac, Wt, cp, bf_, bi_, bg_, bo_, (float*)d_out);
    } else {
        lstm_f32<<<dim3(B_DIM / 128, H_DIM / 32), dim3(256), 0, stream>>>(
            x, hp, cp, Wf, Wi, Wg, Wo, bf_, bi_, bg_, bo_, (float*)d_out);
    }
}

// Round 7
// 201.020 us; speedup vs baseline: 1.5844x; 1.0541x over previous
//
#include <hip/hip_runtime.h>

#define B_DIM 4096
#define H_DIM 1024
#define K_DIM 2048   // IN + H

typedef unsigned short u16;
typedef unsigned int u32;
typedef __attribute__((ext_vector_type(8))) short short8;
typedef __attribute__((ext_vector_type(4))) float f32x4;

typedef const __attribute__((address_space(1))) void* gas_ptr;
typedef __attribute__((address_space(3))) void* las_ptr;

#define WT_ELEMS (4 * H_DIM * K_DIM)       // 8.39M u16
#define AC_ELEMS (B_DIM * K_DIM)           // 8.39M u16
#define WS_NEEDED ((size_t)(WT_ELEMS + AC_ELEMS) * 2)   // 33.55 MB

__device__ __forceinline__ void gl_lds16(const u16* g, u16* l) {
    __builtin_amdgcn_global_load_lds((gas_ptr)g, (las_ptr)l, 16, 0, 0);
}
__device__ __forceinline__ float bf2f(u16 v) {
    return __builtin_bit_cast(float, (u32)((u32)v << 16));
}
__device__ __forceinline__ u16 f2bf(float f) {
    u32 u = __builtin_bit_cast(u32, f);
    return (u16)((u + 0x7fffu + ((u >> 16) & 1u)) >> 16);
}
__device__ __forceinline__ float sigm(float x) { return 1.0f / (1.0f + __expf(-x)); }
__device__ __forceinline__ float tanh_f(float x) { return 1.0f - 2.0f / (__expf(2.0f * x) + 1.0f); }

// ---------- merged prep: blocks [0,4096) convert A; blocks [4096,6144) transpose W ----------
__global__ __launch_bounds__(256) void prep_all(const float* __restrict__ x, const float* __restrict__ h,
                                                const float* __restrict__ Wf, const float* __restrict__ Wi,
                                                const float* __restrict__ Wg, const float* __restrict__ Wo,
                                                u16* __restrict__ A, u16* __restrict__ Wt) {
    __shared__ u16 tl[64][72];
    const int t = threadIdx.x;
    if (blockIdx.x < 4096) {
        int e = (blockIdx.x * 256 + t) * 8;
        int m = e >> 11, c = e & 2047;
        const float* src = (c < 1024) ? (x + (size_t)m * 1024 + c) : (h + (size_t)m * 1024 + (c - 1024));
        float4 v0 = ((const float4*)src)[0], v1 = ((const float4*)src)[1];
        short8 q;
        q[0] = (short)f2bf(v0.x); q[1] = (short)f2bf(v0.y); q[2] = (short)f2bf(v0.z); q[3] = (short)f2bf(v0.w);
        q[4] = (short)f2bf(v1.x); q[5] = (short)f2bf(v1.y); q[6] = (short)f2bf(v1.z); q[7] = (short)f2bf(v1.w);
        *(short8*)(A + e) = q;
    } else {
        int bid = blockIdx.x - 4096;
        const int k0 = (bid & 31) * 64, n0 = ((bid >> 5) & 15) * 64, g = bid >> 9;
        const float* W = (g == 0) ? Wf : (g == 1) ? Wi : (g == 2) ? Wg : Wo;
        {
            int kl = t >> 2, nc = (t & 3) * 16;
            const float4* src = (const float4*)(W + (size_t)(k0 + kl) * H_DIM + n0 + nc);
            float4 v0 = src[0], v1 = src[1], v2 = src[2], v3 = src[3];
            short8 q0, q1;
            q0[0] = (short)f2bf(v0.x); q0[1] = (short)f2bf(v0.y); q0[2] = (short)f2bf(v0.z); q0[3] = (short)f2bf(v0.w);
            q0[4] = (short)f2bf(v1.x); q0[5] = (short)f2bf(v1.y); q0[6] = (short)f2bf(v1.z); q0[7] = (short)f2bf(v1.w);
            q1[0] = (short)f2bf(v2.x); q1[1] = (short)f2bf(v2.y); q1[2] = (short)f2bf(v2.z); q1[3] = (short)f2bf(v2.w);
            q1[4] = (short)f2bf(v3.x); q1[5] = (short)f2bf(v3.y); q1[6] = (short)f2bf(v3.z); q1[7] = (short)f2bf(v3.w);
            *(short8*)&tl[kl][nc] = q0;
            *(short8*)&tl[kl][nc + 8] = q1;
        }
        __syncthreads();
        {
            int nl = t >> 2, kc = (t & 3) * 16;
            short8 r0, r1;
#pragma unroll
            for (int j = 0; j < 8; ++j) { r0[j] = (short)tl[kc + j][nl]; r1[j] = (short)tl[kc + 8 + j][nl]; }
            u16* dst = Wt + (size_t)g * (H_DIM * K_DIM) + (size_t)(n0 + nl) * K_DIM + k0 + kc;
            *(short8*)dst = r0;
            *(short8*)(dst + 8) = r1;
        }
    }
}

// ---------- main fused GEMM + LSTM ----------
// Block tile: 256 batch-rows x (4 gates x 32 H-cols). 256 threads = 4 waves.
// Wave w: rows [w*64,+64), ALL 4 gates, 32 cols -> 64 MFMAs per wave per K-iter
// against the same 2 barriers (2x the MFMA/barrier of round 6). All 4 gate values
// of an output element stay in one lane => pure-register epilogue.
// BK=64; XOR k-slot swizzle: within each 16-lane quad, slot group (s4+quad)^v7 spans
// all 8 groups as l15&7 varies -> 2-way max aliasing = free (0 conflicts, verified r5/r6).
__global__ __launch_bounds__(256, 2) void lstm_gemm(
    const u16* __restrict__ A, const u16* __restrict__ Wt, const float* __restrict__ c_prev,
    const float* __restrict__ bf_, const float* __restrict__ bi_,
    const float* __restrict__ bg_, const float* __restrict__ bo_,
    float* __restrict__ out) {
    __shared__ u16 sA[256 * 64];    // 32 KB  [m][slot]    slot = k8 ^ (m&7)
    __shared__ u16 sB[4 * 32 * 64]; // 16 KB  [g][n][slot] slot = k8 ^ (n&7)

    const int t = threadIdx.x;
    const int w = t >> 6;
    const int l = t & 63;
    const int quad = l >> 4;
    const int l15 = l & 15;
    const int v7 = l15 & 7;
    const int m0 = blockIdx.x * 256;
    const int j0 = blockIdx.y * 32;

    f32x4 acc[8][4];   // [ntile = gate*2 + colhalf][mi]
#pragma unroll
    for (int nt = 0; nt < 8; ++nt)
#pragma unroll
        for (int mi = 0; mi < 4; ++mi)
            acc[nt][mi] = (f32x4){0.f, 0.f, 0.f, 0.f};

    // Hoisted DMA source pointers (advance by 64 u16 per K-iter).
    const u16* pA[8];
    const u16* pB[4];
#pragma unroll
    for (int i = 0; i < 8; ++i) {
        int c = i * 256 + t;
        int m = c >> 3, slot = c & 7;
        pA[i] = A + (size_t)(m0 + m) * K_DIM + (slot ^ (m & 7)) * 8;
    }
#pragma unroll
    for (int i = 0; i < 4; ++i) {
        int c = i * 256 + t;
        int g = c >> 8, r = c & 255;
        int n = r >> 3, slot = r & 7;
        pB[i] = Wt + (size_t)g * (H_DIM * K_DIM) + (size_t)(j0 + n) * K_DIM + (slot ^ (n & 7)) * 8;
    }

    for (int kt = 0; kt < K_DIM / 64; ++kt) {
        __syncthreads();   // prior iteration's frag reads done
#pragma unroll
        for (int i = 0; i < 8; ++i) {
            gl_lds16(pA[i], sA + (i * 256 + t) * 8);
            pA[i] += 64;
        }
#pragma unroll
        for (int i = 0; i < 4; ++i) {
            gl_lds16(pB[i], sB + (i * 256 + t) * 8);
            pB[i] += 64;
        }
        __syncthreads();   // drain DMA before frag reads

#pragma unroll
        for (int s = 0; s < 2; ++s) {
            const int sl = ((s * 4 + quad) ^ v7) * 8;
            short8 afr[4];
#pragma unroll
            for (int mi = 0; mi < 4; ++mi)
                afr[mi] = *(const short8*)(sA + (w * 64 + mi * 16 + l15) * 64 + sl);
            short8 bfr[8];
#pragma unroll
            for (int nt = 0; nt < 8; ++nt)
                bfr[nt] = *(const short8*)(sB + (nt >> 1) * 2048 + ((nt & 1) * 16 + l15) * 64 + sl);
#pragma unroll
            for (int nt = 0; nt < 8; ++nt)
#pragma unroll
                for (int mi = 0; mi < 4; ++mi)
                    acc[nt][mi] = __builtin_amdgcn_mfma_f32_16x16x32_bf16(afr[mi], bfr[nt], acc[nt][mi], 0, 0, 0);
        }
    }

    // -------- register epilogue: no LDS, no barriers --------
#pragma unroll
    for (int ni = 0; ni < 2; ++ni) {
        const int col = j0 + ni * 16 + l15;
        const float bF = bf_[col], bI = bi_[col], bG = bg_[col], bO = bo_[col];
#pragma unroll
        for (int mi = 0; mi < 4; ++mi) {
            const int rowbase = m0 + w * 64 + mi * 16 + quad * 4;  // C/D map: col=lane&15, row=quad*4+reg
            float cp[4];
#pragma unroll
            for (int rr = 0; rr < 4; ++rr)
                cp[rr] = c_prev[(size_t)(rowbase + rr) * H_DIM + col];
#pragma unroll
            for (int rr = 0; rr < 4; ++rr) {
                float fv = sigm(acc[0 + ni][mi][rr] + bF);
                float iv = sigm(acc[2 + ni][mi][rr] + bI);
                float gv = tanh_f(acc[4 + ni][mi][rr] + bG);
                float ov = sigm(acc[6 + ni][mi][rr] + bO);
                float cn = fv * cp[rr] + iv * gv;
                float hn = ov * tanh_f(cn);
                size_t idx = (size_t)(rowbase + rr) * H_DIM + col;
                out[idx] = hn;
                out[(size_t)B_DIM * H_DIM + idx] = cn;
            }
        }
    }
}

// ---------- fallback (round-3 passing kernel): used only if ws too small ----------
__global__ __launch_bounds__(256) void lstm_f32(
    const float* __restrict__ x, const float* __restrict__ h_prev, const float* __restrict__ c_prev,
    const float* __restrict__ Wf, const float* __restrict__ Wi, const float* __restrict__ Wg, const float* __restrict__ Wo,
    const float* __restrict__ bf_, const float* __restrict__ bi_, const float* __restrict__ bg_, const float* __restrict__ bo_,
    float* __restrict__ out) {
    __shared__ u16 smem[16384];
    u16* sA = smem;
    u16* sB = smem + 4096;

    const int t = threadIdx.x;
    const int w = t >> 6;
    const int l = t & 63;
    const int quad = l >> 4;
    const int l15 = l & 15;
    const int wr = w >> 1;
    const int wc = w & 1;
    const int m0 = blockIdx.x * 128;
    const int j0 = blockIdx.y * 32;

    const int arow = t >> 1;
    const int akh = (t & 1) * 16;
    const int r7 = t & 127;
    const int bk = r7 >> 2;
    const int bn8 = (r7 & 3) * 8;
    const int kswz = ((((bk >> 3) ^ (bn8 >> 3)) << 3) | (bk & 7));
    const float* WpA = (t < 128) ? Wf : Wi;
    const float* WpB = (t < 128) ? Wg : Wo;
    const int gA = (t >> 7);
    const int gB = 2 + (t >> 7);

    f32x4 acc[2][4][2];
#pragma unroll
    for (int gi = 0; gi < 2; ++gi)
#pragma unroll
        for (int mi = 0; mi < 4; ++mi)
#pragma unroll
            for (int ni = 0; ni < 2; ++ni)
                acc[gi][mi][ni] = (f32x4){0.f, 0.f, 0.f, 0.f};

    for (int kt = 0; kt < K_DIM / 32; ++kt) {
        const float* srcA = (kt < 32) ? x : h_prev;
        const int koff = (kt & 31) * 32;
        __syncthreads();

        const float4* ap = (const float4*)(srcA + (size_t)(m0 + arow) * H_DIM + koff + akh);
        float4 a0 = ap[0], a1 = ap[1], a2 = ap[2], a3 = ap[3];
        short8 p0, p1;
        p0[0] = (short)f2bf(a0.x); p0[1] = (short)f2bf(a0.y); p0[2] = (short)f2bf(a0.z); p0[3] = (short)f2bf(a0.w);
        p0[4] = (short)f2bf(a1.x); p0[5] = (short)f2bf(a1.y); p0[6] = (short)f2bf(a1.z); p0[7] = (short)f2bf(a1.w);
        p1[0] = (short)f2bf(a2.x); p1[1] = (short)f2bf(a2.y); p1[2] = (short)f2bf(a2.z); p1[3] = (short)f2bf(a2.w);
        p1[4] = (short)f2bf(a3.x); p1[5] = (short)f2bf(a3.y); p1[6] = (short)f2bf(a3.z); p1[7] = (short)f2bf(a3.w);
        *(short8*)(sA + arow * 32 + akh) = p0;
        *(short8*)(sA + arow * 32 + akh + 8) = p1;

        const float* gpA = WpA + (size_t)(kt * 32 + bk) * H_DIM + j0 + bn8;
        const float* gpB = WpB + (size_t)(kt * 32 + bk) * H_DIM + j0 + bn8;
        float4 c0 = *(const float4*)gpA, c1 = *(const float4*)(gpA + 4);
        float4 d0 = *(const float4*)gpB, d1 = *(const float4*)(gpB + 4);
        sB[gA * 1024 + (bn8 + 0) * 32 + kswz] = f2bf(c0.x);
        sB[gA * 1024 + (bn8 + 1) * 32 + kswz] = f2bf(c0.y);
        sB[gA * 1024 + (bn8 + 2) * 32 + kswz] = f2bf(c0.z);
        sB[gA * 1024 + (bn8 + 3) * 32 + kswz] = f2bf(c0.w);
        sB[gA * 1024 + (bn8 + 4) * 32 + kswz] = f2bf(c1.x);
        sB[gA * 1024 + (bn8 + 5) * 32 + kswz] = f2bf(c1.y);
        sB[gA * 1024 + (bn8 + 6) * 32 + kswz] = f2bf(c1.z);
        sB[gA * 1024 + (bn8 + 7) * 32 + kswz] = f2bf(c1.w);
        sB[gB * 1024 + (bn8 + 0) * 32 + kswz] = f2bf(d0.x);
        sB[gB * 1024 + (bn8 + 1) * 32 + kswz] = f2bf(d0.y);
        sB[gB * 1024 + (bn8 + 2) * 32 + kswz] = f2bf(d0.z);
        sB[gB * 1024 + (bn8 + 3) * 32 + kswz] = f2bf(d0.w);
        sB[gB * 1024 + (bn8 + 4) * 32 + kswz] = f2bf(d1.x);
        sB[gB * 1024 + (bn8 + 5) * 32 + kswz] = f2bf(d1.y);
        sB[gB * 1024 + (bn8 + 6) * 32 + kswz] = f2bf(d1.z);
        sB[gB * 1024 + (bn8 + 7) * 32 + kswz] = f2bf(d1.w);
        __syncthreads();

        short8 bfr[2][2];
#pragma unroll
        for (int gi = 0; gi < 2; ++gi) {
            int g = wc * 2 + gi;
#pragma unroll
            for (int ni = 0; ni < 2; ++ni) {
                int n = ni * 16 + l15;
                bfr[gi][ni] = *(const short8*)(sB + g * 1024 + n * 32 + ((quad ^ (n >> 3)) * 8));
            }
        }
#pragma unroll
        for (int mi = 0; mi < 4; ++mi) {
            int m = wr * 64 + mi * 16 + l15;
            short8 afr = *(const short8*)(sA + m * 32 + quad * 8);
#pragma unroll
            for (int gi = 0; gi < 2; ++gi)
#pragma unroll
                for (int ni = 0; ni < 2; ++ni)
                    acc[gi][mi][ni] =
                        __builtin_amdgcn_mfma_f32_16x16x32_bf16(afr, bfr[gi][ni], acc[gi][mi][ni], 0, 0, 0);
        }
    }

    __syncthreads();
#pragma unroll
    for (int gi = 0; gi < 2; ++gi) {
        int g = wc * 2 + gi;
        const float* bp = (g == 0) ? bf_ : (g == 1) ? bi_ : (g == 2) ? bg_ : bo_;
#pragma unroll
        for (int ni = 0; ni < 2; ++ni) {
            int col = ni * 16 + l15;
            float bias = bp[j0 + col];
#pragma unroll
            for (int mi = 0; mi < 4; ++mi)
#pragma unroll
                for (int rr = 0; rr < 4; ++rr) {
                    int row = wr * 64 + mi * 16 + quad * 4 + rr;
                    float v = acc[gi][mi][ni][rr] + bias;
                    v = (g == 2) ? tanh_f(v) : sigm(v);
                    smem[g * 4096 + row * 32 + col] = f2bf(v);
                }
        }
    }
    __syncthreads();

    const int col = t & 31;
    const int rb = t >> 5;
#pragma unroll
    for (int p = 0; p < 16; ++p) {
        int row = p * 8 + rb;
        float fv = bf2f(smem[0 * 4096 + row * 32 + col]);
        float iv = bf2f(smem[1 * 4096 + row * 32 + col]);
        float gv = bf2f(smem[2 * 4096 + row * 32 + col]);
        float ov = bf2f(smem[3 * 4096 + row * 32 + col]);
        size_t oidx = (size_t)(m0 + row) * H_DIM + j0 + col;
        float cp = c_prev[oidx];
        float cn = fv * cp + iv * gv;
        float hn = ov * tanh_f(cn);
        out[oidx] = hn;
        out[(size_t)B_DIM * H_DIM + oidx] = cn;
    }
}

extern "C" void kernel_launch(void* const* d_in, const int* in_sizes, int n_in,
                              void* d_out, int out_size, void* d_ws, size_t ws_size,
                              hipStream_t stream) {
    const float* x   = (const float*)d_in[0];
    const float* hp  = (const float*)d_in[1];
    const float* cp  = (const float*)d_in[2];
    const float* Wf  = (const float*)d_in[3];
    const float* bf_ = (const float*)d_in[4];
    const float* Wi  = (const float*)d_in[5];
    const float* bi_ = (const float*)d_in[6];
    const float* Wg  = (const float*)d_in[7];
    const float* bg_ = (const float*)d_in[8];
    const float* Wo  = (const float*)d_in[9];
    const float* bo_ = (const float*)d_in[10];

    if (ws_size >= WS_NEEDED) {
        u16* Wt = (u16*)d_ws;
        u16* Ac = (u16*)d_ws + WT_ELEMS;
        prep_all<<<dim3(4096 + 2048), dim3(256), 0, stream>>>(x, hp, Wf, Wi, Wg, Wo, Ac, Wt);
        lstm_gemm<<<dim3(B_DIM / 256, H_DIM / 32), dim3(256), 0, stream>>>(
            Ac, Wt, cp, bf_, bi_, bg_, bo_, (float*)d_out);
    } else {
        lstm_f32<<<dim3(B_DIM / 128, H_DIM / 32), dim3(256), 0, stream>>>(
            x, hp, cp, Wf, Wi, Wg, Wo, bf_, bi_, bg_, bo_, (float*)d_out);
    }
}